// Round 8
// baseline (710.979 us; speedup 1.0000x reference)
//
#include <hip/hip_runtime.h>
#include <stdint.h>

#define B_  256
#define T_  512
#define H_  128
#define NSW 6

typedef __bf16 bf2_t __attribute__((ext_vector_type(2)));

// float -> bf16 round-to-nearest-even
__device__ __forceinline__ unsigned short f2bf(float f){
  unsigned u = __float_as_uint(f);
  unsigned r = u + 0x7FFFu + ((u >> 16) & 1u);
  return (unsigned short)(r >> 16);
}

// acc += dot2(bf16x2 w, bf16x2 h)
__device__ __forceinline__ float dot2bf(unsigned wpair, unsigned hpair, float acc){
#if __has_builtin(__builtin_amdgcn_fdot2_f32_bf16)
  return __builtin_amdgcn_fdot2_f32_bf16(__builtin_bit_cast(bf2_t, wpair),
                                         __builtin_bit_cast(bf2_t, hpair), acc, false);
#else
  asm("v_dot2_f32_bf16 %0, %1, %2, %0" : "+v"(acc) : "v"(wpair), "v"(hpair));
  return acc;
#endif
}

// LDS-only barrier: drains lgkmcnt but NOT vmcnt -> in-flight global loads survive.
__device__ __forceinline__ void lds_barrier(){
  asm volatile("s_waitcnt lgkmcnt(0)\ns_barrier" ::: "memory");
}

// Pack: uint4 index = g*12288 + s*2048 + q*512 + j*128 + i
//       holds bf16 of W_g[s][i][32q + 8j + 0..7]
__global__ __launch_bounds__(256) void pack_weights(const float* __restrict__ Wr,
                                                    const float* __restrict__ Wz,
                                                    const float* __restrict__ Wn,
                                                    uint4* __restrict__ dst){
  int idx = blockIdx.x * 256 + threadIdx.x;
  if (idx >= 3 * NSW * 16 * 128) return;   // 36864
  int i  = idx & 127;
  int j  = (idx >> 7) & 3;
  int q  = (idx >> 9) & 3;
  int gs = idx >> 11;            // g*6+s, < 18
  int s  = gs % NSW;
  int g  = gs / NSW;
  const float* W = (g == 0) ? Wr : (g == 1) ? Wz : Wn;
  const float* src = W + (size_t)s * (H_*H_) + (size_t)i * H_ + q * 32 + j * 8;
  uint4 o;
  o.x = (unsigned)f2bf(src[0]) | ((unsigned)f2bf(src[1]) << 16);
  o.y = (unsigned)f2bf(src[2]) | ((unsigned)f2bf(src[3]) << 16);
  o.z = (unsigned)f2bf(src[4]) | ((unsigned)f2bf(src[5]) << 16);
  o.w = (unsigned)f2bf(src[6]) | ((unsigned)f2bf(src[7]) << 16);
  dst[idx] = o;
}

// 512 threads: thread (q = tid>>7, i = tid&127) computes ALL THREE gate
// partial sums for row i over k in [32q, 32q+32). Partials combined in LDS.
__global__ __launch_bounds__(512, 1) void gru_run(const float* __restrict__ stim,
    const int*   __restrict__ swid,  const float* __restrict__ mask,
    const float* __restrict__ Win,   const float* __restrict__ binp,
    const float* __restrict__ b_hr,  const float* __restrict__ b_hz, const float* __restrict__ b_hn,
    const float* __restrict__ Wo,    const float* __restrict__ bo,
    const uint4* __restrict__ Wpk,   float* __restrict__ out)
{
  const int b    = blockIdx.x;
  const int tid  = threadIdx.x;
  const int q    = tid >> 7;
  const int i    = tid & 127;
  const int lane = tid & 63;

  __shared__ float    s_stim[T_ * 8];       // 16 KB
  __shared__ float    s_mask[T_];           //  2 KB
  __shared__ int      s_sid[T_];            //  2 KB
  __shared__ float    s_b[3 * NSW * H_];    //  9 KB
  __shared__ float    s_part[3 * 4 * H_];   //  6 KB  [g][q][i]
  __shared__ float    s_h[2][H_];           // fp32 h state
  __shared__ unsigned s_hb[2][64];          // h as bf16 pairs

  // ---- preload chain-local data ----
  for (int k = tid; k < T_ * 8; k += 512) s_stim[k] = stim[(size_t)b * T_ * 8 + k];
  for (int k = tid; k < T_; k += 512){
    s_mask[k] = mask[(size_t)b * T_ + k];
    int ss = swid[(size_t)b * T_ + k];
    s_sid[k] = ss < 0 ? 0 : (ss > NSW - 1 ? NSW - 1 : ss);
  }
  for (int k = tid; k < NSW * H_; k += 512){
    s_b[k]                = b_hr[k];
    s_b[NSW * H_ + k]     = b_hz[k];
    s_b[2 * NSW * H_ + k] = b_hn[k];
  }
  if (tid < H_) s_h[0][tid] = 0.f;
  if (tid < 64) s_hb[0][tid] = 0u;

  // input-projection rows for outputs i, 128+i, 256+i (used by q==0 only;
  // all threads load valid addresses)
  float winr[24];
  #pragma unroll
  for (int g2 = 0; g2 < 3; ++g2)
    #pragma unroll
    for (int e = 0; e < 8; ++e)
      winr[g2 * 8 + e] = Win[(size_t)(g2 * H_ + i) * 8 + e];
  float binr3[3];
  #pragma unroll
  for (int g2 = 0; g2 < 3; ++g2) binr3[g2] = binp[g2 * H_ + i];

  // logit weights for q==1 (waves 2,3): wave2 -> logit0, wave3 -> logit1
  float wo_a = 0.f, wo_b = 0.f, bo_r = 0.f;
  const int kk = (tid >= 192 && tid < 256) ? 1 : 0;
  if (q == 1){
    wo_a = Wo[kk * H_ + lane];
    wo_b = Wo[kk * H_ + 64 + lane];
    bo_r = bo[kk];
  }

  const uint4* G0 = Wpk + 0 * 12288 + q * 512 + i;
  const uint4* G1 = Wpk + 1 * 12288 + q * 512 + i;
  const uint4* G2 = Wpk + 2 * 12288 + q * 512 + i;
  float* outp = out + (size_t)b * T_ * 2;

  __syncthreads();

  // sid pipeline in SGPRs
  int sc = __builtin_amdgcn_readfirstlane(s_sid[0]);
  int sn = __builtin_amdgcn_readfirstlane(s_sid[1]);

  // prologue: load step-0 weights (single buffer: 12 x uint4 = 48 VGPRs)
  uint4 wr[4], wz[4], wn[4];
  {
    const uint4 *p0 = G0 + (size_t)sc * 2048, *p1 = G1 + (size_t)sc * 2048,
                *p2 = G2 + (size_t)sc * 2048;
    #pragma unroll
    for (int j = 0; j < 4; ++j){ wr[j] = p0[j*128]; wz[j] = p1[j*128]; wn[j] = p2[j*128]; }
  }

  #pragma unroll 1
  for (int t = 0; t < T_; ++t){
    const int cur = t & 1, nxt = cur ^ 1;

    // h pairs for this quarter: lanes 0..15 hold pairs 16q..16q+15 (dup x4)
    unsigned hp = s_hb[cur][(q << 4) + (lane & 15)];

    float ar = 0.f, az = 0.f, an = 0.f;
    #pragma unroll
    for (int j = 0; j < 4; ++j){
      unsigned h0 = (unsigned)__builtin_amdgcn_readlane((int)hp, 4*j + 0);
      unsigned h1 = (unsigned)__builtin_amdgcn_readlane((int)hp, 4*j + 1);
      unsigned h2 = (unsigned)__builtin_amdgcn_readlane((int)hp, 4*j + 2);
      unsigned h3 = (unsigned)__builtin_amdgcn_readlane((int)hp, 4*j + 3);
      ar = dot2bf(wr[j].x, h0, ar); az = dot2bf(wz[j].x, h0, az); an = dot2bf(wn[j].x, h0, an);
      ar = dot2bf(wr[j].y, h1, ar); az = dot2bf(wz[j].y, h1, az); an = dot2bf(wn[j].y, h1, an);
      ar = dot2bf(wr[j].z, h2, ar); az = dot2bf(wz[j].z, h2, az); an = dot2bf(wn[j].z, h2, an);
      ar = dot2bf(wr[j].w, h3, ar); az = dot2bf(wz[j].w, h3, az); an = dot2bf(wn[j].w, h3, an);
    }
    s_part[(0*4 + q) * H_ + i] = ar;
    s_part[(1*4 + q) * H_ + i] = az;
    s_part[(2*4 + q) * H_ + i] = an;

    // next-step sid (consumed at step end)
    int tn2 = (t + 2 < T_) ? t + 2 : T_ - 1;
    int snl = s_sid[tn2];

    // prefetch next step's weights into the SAME buffer (regs dead after dot2s).
    // Best case: overlaps epilogue+barriers. Worst case (compiler sinks to
    // next-iteration use): identical to load-at-top.
    {
      const uint4 *p0 = G0 + (size_t)sn * 2048, *p1 = G1 + (size_t)sn * 2048,
                  *p2 = G2 + (size_t)sn * 2048;
      #pragma unroll
      for (int j = 0; j < 4; ++j){ wr[j] = p0[j*128]; wz[j] = p1[j*128]; wn[j] = p2[j*128]; }
    }

    lds_barrier();   // B1: partials visible

    if (q == 0){
      float hr = ar + s_part[1*H_ + i] + s_part[2*H_ + i] + s_part[3*H_ + i]
               + s_b[0*(NSW*H_) + sc*H_ + i];
      float hz = az + s_part[(4+1)*H_ + i] + s_part[(4+2)*H_ + i] + s_part[(4+3)*H_ + i]
               + s_b[1*(NSW*H_) + sc*H_ + i];
      float hn = an + s_part[(8+1)*H_ + i] + s_part[(8+2)*H_ + i] + s_part[(8+3)*H_ + i]
               + s_b[2*(NSW*H_) + sc*H_ + i];
      float4 sa = *reinterpret_cast<const float4*>(&s_stim[t * 8]);
      float4 sb = *reinterpret_cast<const float4*>(&s_stim[t * 8 + 4]);
      float xr = binr3[0] + winr[0]*sa.x + winr[1]*sa.y + winr[2]*sa.z + winr[3]*sa.w
                          + winr[4]*sb.x + winr[5]*sb.y + winr[6]*sb.z + winr[7]*sb.w;
      float xz = binr3[1] + winr[8]*sa.x + winr[9]*sa.y + winr[10]*sa.z + winr[11]*sa.w
                          + winr[12]*sb.x + winr[13]*sb.y + winr[14]*sb.z + winr[15]*sb.w;
      float xn = binr3[2] + winr[16]*sa.x + winr[17]*sa.y + winr[18]*sa.z + winr[19]*sa.w
                          + winr[20]*sb.x + winr[21]*sb.y + winr[22]*sb.z + winr[23]*sb.w;
      float r = 1.f / (1.f + __expf(-(xr + hr)));
      float z = 1.f / (1.f + __expf(-(xz + hz)));
      float e = __expf(2.f * (xn + r * hn));      // tanh(a) = 1 - 2/(e^{2a}+1)
      float n = 1.f - 2.f / (e + 1.f);
      float hprev = s_h[cur][i];
      float hnew  = (1.f - z) * n + z * hprev;
      float mt    = s_mask[t];
      float ho    = mt * hnew + (1.f - mt) * hprev;
      s_h[nxt][i] = ho;
      ((unsigned short*)s_hb[nxt])[i] = f2bf(ho);
    }

    lds_barrier();   // B2: h_out visible

    if (q == 1){
      float p = wo_a * s_h[nxt][lane] + wo_b * s_h[nxt][64 + lane];
      p += __shfl_down(p, 32); p += __shfl_down(p, 16); p += __shfl_down(p, 8);
      p += __shfl_down(p, 4);  p += __shfl_down(p, 2);  p += __shfl_down(p, 1);
      if (lane == 0) outp[t * 2 + kk] = p + bo_r;
    }

    sc = sn;
    sn = __builtin_amdgcn_readfirstlane(snl);
  }
}

extern "C" void kernel_launch(void* const* d_in, const int* in_sizes, int n_in,
                              void* d_out, int out_size, void* d_ws, size_t ws_size,
                              hipStream_t stream) {
  const float* stim = (const float*)d_in[0];
  const int*   swid = (const int*)  d_in[1];
  const float* mask = (const float*)d_in[2];
  const float* Win  = (const float*)d_in[3];
  const float* binp = (const float*)d_in[4];
  const float* Whr  = (const float*)d_in[5];
  const float* Whz  = (const float*)d_in[6];
  const float* Whn  = (const float*)d_in[7];
  const float* bhr  = (const float*)d_in[8];
  const float* bhz  = (const float*)d_in[9];
  const float* bhn  = (const float*)d_in[10];
  const float* Wo   = (const float*)d_in[11];
  const float* bo   = (const float*)d_in[12];

  uint4* wpk = (uint4*)d_ws;   // 589824 bytes used

  pack_weights<<<144, 256, 0, stream>>>(Whr, Whz, Whn, wpk);
  gru_run<<<B_, 512, 0, stream>>>(stim, swid, mask, Win, binp,
                                  bhr, bhz, bhn, Wo, bo, wpk, (float*)d_out);
}